// Round 11
// baseline (222.947 us; speedup 1.0000x reference)
//
#include <hip/hip_runtime.h>

// VQ-VAE vector quantizer, MI355X (gfx950).
//   inputs : z (8,256,16,16,16) fp32, codebook (1024,256) fp32
//   output : quant (8,256,16,16,16) ++ idx (8,16,16,16) ++ loss (1), fp32 flat
//
// Round 17 = r16 resubmit (r16's bench died on container acquisition, not on
//   the kernel: no pytest/absmax/rocprof evidence; kernel audit found no
//   hang mechanism -- bounded loops, non-divergent barriers, legal LDS/occ,
//   ds_min_rtn_u64 supported). Theory unchanged:
//   Work-queue recheck. r15 put z in LDS and DE stayed 75us (=r14's bare D)
//   -> D's cost is serial-work distribution: per-candidate 256-deep fmaf
//   chains on single lanes, and dominant, the overflow path (cnt>CAP => ONE
//   wave runs 16 sequential full dots/lane; one such token pins the whole
//   block at the pre-E barrier). Fix: flatten all exact dots into a
//   block-wide task list (token t -> cnt[t] tasks, or 1024 if overflow),
//   prefix-sum + binary search task->(t,j), round-robin over 512 lanes; each
//   task = UNCHANGED exact ascending-d fmaf chain (z from verified LDS slab,
//   e from L2); merge via LDS atomicMin on order-preserving packed key
//   (ukey(D)<<32)|k == bit-exact lex-min (D,k) (monotone float->uint map;
//   D==-0.0 impossible under RN; ties -> smaller k). Overflow: 2 chains/lane
//   instead of 16-serial on one wave. prep/filter/slab-loader/epilogue
//   byte-identical to r15 (verified).

#define K_CODES 1024
#define DIM 256
#define N_TOK 32768
#define SPATIAL 4096
#define TOK_BLK 64
#define NBLK (N_TOK / TOK_BLK)
#define CAP 28
#define MARGIN 1e-3f
#define ZLD 257  // z-slab row stride (floats): bank = (tok + d) % 32

typedef __attribute__((ext_vector_type(8))) short short8;
typedef __attribute__((ext_vector_type(4))) float float4v;

// ws layout in floats
#define WS_LOSS 0
#define WS_CNT 8         // unsigned completion counter (DE blocks)
#define WS_E2 16         // 1024 floats: Se[k] (np pairwise)
#define WS_EB 2048       // 262144 bf16: codebook, B-fragment order
#define WS_SZ 133120     // 32768 floats: Sz per token (blk0+blk1 combined)
#define WS_CAND 165888   // 32768*28 u16 candidate ids (458752 floats)
#define WS_CCNT 624640   // 32768 ints: candidate counts (raw, may exceed CAP)

#define O_IDX (8 * DIM * SPATIAL)  // 8388608
#define O_LOSS (O_IDX + N_TOK)     // 8421376

__device__ __forceinline__ short f2bf(float v) {  // RTNE fp32->bf16 bits
  unsigned u = __float_as_uint(v);
  u = (u + 0x7fffu + ((u >> 16) & 1u)) >> 16;
  return (short)u;
}

__device__ __forceinline__ unsigned long long packDK(float D, int k) {
  // strictly monotone float->uint map; lex-min (D,k) == min of packed
  unsigned ds = __float_as_uint(D);
  unsigned key = (ds & 0x80000000u) ? ~ds : (ds ^ 0x80000000u);
  return ((unsigned long long)key << 32) | (unsigned)k;
}

// prep: Se[k] np-pairwise (exact order, parallelized); codebook -> bf16 in
// MFMA B-fragment order, 16B chunk stores.  (verified rounds 7-15)
__global__ __launch_bounds__(256) void prep_kernel(const float* __restrict__ e,
                                                   float* __restrict__ ws) {
  __shared__ float sq[DIM];
  __shared__ __align__(16) short sbf[DIM];
  __shared__ float chv[16];
  int k = blockIdx.x, d = threadIdx.x;
  float v = e[k * DIM + d];
  sbf[d] = f2bf(v);
  sq[d] = __fmul_rn(v, v);
  __syncthreads();
  if (d < 32) {  // 16B chunk stores of the fragment layout
    int f = d >> 2, q = d & 3;
    int stage = k >> 6, ct = (k >> 4) & 3, nn = k & 15;
    short8 chunk = *(const short8*)(sbf + f * 32 + q * 8);
    int off8 = ((stage * 4 + ct) * 8 + f) * 64 + q * 16 + nn;
    ((short8*)(ws + WS_EB))[off8] = chunk;
  }
  if (d < 16) {  // chain (blk=d>>3, j=d&7): exact np serial order i=0..15
    int blkb = d >> 3, j = d & 7;
    const float* x = sq + blkb * 128;
    float c = x[j];
#pragma unroll
    for (int i = 1; i < 16; i++) c = __fadd_rn(c, x[i * 8 + j]);
    chv[d] = c;
  }
  __syncthreads();
  if (d == 0) {  // exact np_pairwise128 combine tree, then blk0+blk1
    float a0 = __fadd_rn(__fadd_rn(chv[0], chv[1]), __fadd_rn(chv[2], chv[3]));
    float a1 = __fadd_rn(__fadd_rn(chv[4], chv[5]), __fadd_rn(chv[6], chv[7]));
    float resA = __fadd_rn(a0, a1);
    float b0 = __fadd_rn(__fadd_rn(chv[8], chv[9]), __fadd_rn(chv[10], chv[11]));
    float b1 = __fadd_rn(__fadd_rn(chv[12], chv[13]), __fadd_rn(chv[14], chv[15]));
    float resB = __fadd_rn(b0, b1);
    ws[WS_E2 + k] = __fadd_rn(resA, resB);
    if (k == 0) {
      ws[WS_LOSS] = 0.f;
      ((unsigned*)ws)[WS_CNT] = 0u;
    }
  }
}

// ---- Kernel C: Sz + A-frags + MFMA filter (r13/r14-verified), spill ----
__global__ __launch_bounds__(512, 4) void filter_kernel(const float* __restrict__ z,
                                                        float* __restrict__ ws) {
  __shared__ __align__(16) short Bst[64 * 256];  // 32 KB, fragment order
  __shared__ unsigned short cand[TOK_BLK][CAP];
  __shared__ int cnt[TOK_BLK];
  __shared__ float Szp[2][TOK_BLK];  // per-128-dim-block Sz partials

  int tid = threadIdx.x, w = tid >> 6, lane = tid & 63;
  int quad = lane >> 4, nn = lane & 15;
  int g = w & 3, kh = w >> 2;  // token group (16 tokens), codebook half
  int n0 = blockIdx.x * TOK_BLK;
  int b = n0 >> 12, s0 = n0 & 4095;
  const float* zb = z + (size_t)b * DIM * SPATIAL + s0;
  const float* Se = ws + WS_E2;
  const uint4* eBg = (const uint4*)(ws + WS_EB);
  if (tid < TOK_BLK) cnt[tid] = 0;

  // ---- Sz partial (exact np pairwise): wave kh does dim-block kh (128 d)
  //      for its 16 tokens; merge tree = exact np pairing (r8/r11-verified) ----
  {
    const float* zp = zb + g * 16 + nn;
    float r0, r1;
    {
      int j0 = quad * 2;
      float v0 = zp[(size_t)(kh * 128 + j0) * SPATIAL];
      float v1 = zp[(size_t)(kh * 128 + j0 + 1) * SPATIAL];
      r0 = __fmul_rn(v0, v0);
      r1 = __fmul_rn(v1, v1);
      for (int i = 1; i < 16; i++) {
        v0 = zp[(size_t)(kh * 128 + i * 8 + j0) * SPATIAL];
        v1 = zp[(size_t)(kh * 128 + i * 8 + j0 + 1) * SPATIAL];
        r0 = __fadd_rn(r0, __fmul_rn(v0, v0));
        r1 = __fadd_rn(r1, __fmul_rn(v1, v1));
      }
    }
    float p = __fadd_rn(r0, r1);                    // (c_{2q} + c_{2q+1})
    float s1 = __fadd_rn(p, __shfl_xor(p, 16));     // (p0+p1) | (p2+p3)
    float s2 = __fadd_rn(s1, __shfl_xor(s1, 32));   // np_pairwise128 result
    if (quad == 0) Szp[kh][g * 16 + nn] = s2;
  }

  // ---- A fragments (z -> bf16): token m = g*16+nn, frag f holds
  //      k-dim d = f*32 + quad*8 + j ----
  int tokA = g * 16 + nn;
  short8 A[8];
#pragma unroll
  for (int f = 0; f < 8; f++) {
    short8 a;
#pragma unroll
    for (int j = 0; j < 8; j++) {
      int d = f * 32 + quad * 8 + j;
      a[j] = f2bf(zb[(size_t)d * SPATIAL + tokA]);
    }
    A[f] = a;
  }

  // ---- Phase C: MFMA filter, 16 stages, paired cts (r13-verified) ----
  float thr[4] = {3.4e38f, 3.4e38f, 3.4e38f, 3.4e38f};
  for (int stage = 0; stage < 16; stage++) {
    __syncthreads();  // prior-stage LDS reads done (also orders cnt=0, Szp)
#pragma unroll
    for (int i = 0; i < 4; i++)  // 32 KB via 512 threads: reg round-trip
      ((uint4*)Bst)[i * 512 + tid] = eBg[(size_t)stage * 2048 + i * 512 + tid];
    __syncthreads();  // data ready

    int ct0 = kh * 2, ct1 = kh * 2 + 1;
    int kbase0 = stage * 64 + ct0 * 16;
    int kbase1 = stage * 64 + ct1 * 16;
    float4v C0 = {0.f, 0.f, 0.f, 0.f};
    float4v C1 = {0.f, 0.f, 0.f, 0.f};
    const short8* Bp0 = (const short8*)Bst + ct0 * 8 * 64;
    const short8* Bp1 = (const short8*)Bst + ct1 * 8 * 64;
#pragma unroll
    for (int f = 0; f < 8; f++) {  // two independent chains, interleaved
      short8 B0 = Bp0[f * 64 + lane];  // ds_read_b128, conflict-free
      short8 B1 = Bp1[f * 64 + lane];
      C0 = __builtin_amdgcn_mfma_f32_16x16x32_bf16(A[f], B0, C0, 0, 0, 0);
      C1 = __builtin_amdgcn_mfma_f32_16x16x32_bf16(A[f], B1, C1, 0, 0, 0);
    }
    float SeK0 = Se[kbase0 + nn];  // col = code = nn
    float SeK1 = Se[kbase1 + nn];
    float s0v[4], s1v[4], m0[4], m1[4];
#pragma unroll
    for (int r = 0; r < 4; r++) {  // row = token = quad*4 + r
      s0v[r] = fmaf(-2.f, C0[r], SeK0);
      s1v[r] = fmaf(-2.f, C1[r], SeK1);
      m0[r] = s0v[r];
      m1[r] = s1v[r];
    }
#pragma unroll
    for (int dlt = 1; dlt <= 8; dlt <<= 1) {  // 8 independent rowmin chains
#pragma unroll
      for (int r = 0; r < 4; r++) {
        m0[r] = fminf(m0[r], __shfl_xor(m0[r], dlt, 16));
        m1[r] = fminf(m1[r], __shfl_xor(m1[r], dlt, 16));
      }
    }
    // ---- ct0: thr update + append (r11/r13 order) ----
    bool pr[4];
#pragma unroll
    for (int r = 0; r < 4; r++) {
      thr[r] = fminf(thr[r], m0[r]);
      pr[r] = s0v[r] < thr[r] + MARGIN;
    }
    if (__ballot(pr[0] | pr[1] | pr[2] | pr[3])) {  // rare path
#pragma unroll
      for (int r = 0; r < 4; r++) {
        unsigned long long bl = __ballot(pr[r]);
        unsigned grp = (unsigned)((bl >> (quad * 16)) & 0xffffULL);
        if (grp) {  // quad-uniform
          int tb = g * 16 + quad * 4 + r;
          int base = 0;
          if (nn == 0) base = atomicAdd(&cnt[tb], __popc(grp));
          base = __shfl(base, quad * 16);  // broadcast from quad's lane 0
          if (pr[r]) {
            int pos = base + __popc(grp & ((1u << nn) - 1u));
            if (pos < CAP) cand[tb][pos] = (unsigned short)(kbase0 + nn);
          }
        }
      }
    }
    // ---- ct1: thr update + append ----
#pragma unroll
    for (int r = 0; r < 4; r++) {
      thr[r] = fminf(thr[r], m1[r]);
      pr[r] = s1v[r] < thr[r] + MARGIN;
    }
    if (__ballot(pr[0] | pr[1] | pr[2] | pr[3])) {  // rare path
#pragma unroll
      for (int r = 0; r < 4; r++) {
        unsigned long long bl = __ballot(pr[r]);
        unsigned grp = (unsigned)((bl >> (quad * 16)) & 0xffffULL);
        if (grp) {  // quad-uniform
          int tb = g * 16 + quad * 4 + r;
          int base = 0;
          if (nn == 0) base = atomicAdd(&cnt[tb], __popc(grp));
          base = __shfl(base, quad * 16);  // broadcast from quad's lane 0
          if (pr[r]) {
            int pos = base + __popc(grp & ((1u << nn) - 1u));
            if (pos < CAP) cand[tb][pos] = (unsigned short)(kbase1 + nn);
          }
        }
      }
    }
  }
  __syncthreads();  // cnt + cand complete across all waves

  // ---- spill per-token state: token t = tid>>3, slot j = tid&7 ----
  {
    int t = tid >> 3, j = tid & 7;
    int cv = cnt[t];
    if (j == 0) ((int*)ws)[WS_CCNT + n0 + t] = cv;
    if (j == 1)  // Sz total: exact blk0+blk1 (same op D uses; bit-identical)
      ws[WS_SZ + n0 + t] = __fadd_rn(Szp[0][t], Szp[1][t]);
    int cl = cv < CAP ? cv : CAP;
    unsigned short* cg = (unsigned short*)(ws + WS_CAND) + (size_t)(n0 + t) * CAP;
    for (int c = j; c < cl; c += 8) cg[c] = cand[t][c];
  }
}

// ---- Kernel DE: z-slab in LDS + work-queue exact recheck + epilogue. ----
__global__ __launch_bounds__(512, 4) void de_kernel(const float* __restrict__ z,
                                                    const float* __restrict__ e,
                                                    float* __restrict__ ws,
                                                    float* __restrict__ out) {
  __shared__ float zs[TOK_BLK * ZLD];           // 64 x 257 fp32 z-slab (66 KB)
  __shared__ unsigned long long best[TOK_BLK];  // packed (key(D)<<32)|k
  __shared__ int pre[TOK_BLK + 1];              // task prefix sum
  __shared__ int cntl[TOK_BLK];                 // raw counts
  __shared__ float Szs[TOK_BLK];
  __shared__ int mini_sh[TOK_BLK];
  __shared__ float red[8];

  int tid = threadIdx.x, w = tid >> 6, lane = tid & 63;
  int n0 = blockIdx.x * TOK_BLK;
  int b = n0 >> 12, s0 = n0 & 4095;
  const float* zb = z + (size_t)b * DIM * SPATIAL + s0;
  const float* Se = ws + WS_E2;
  const unsigned short* candg = (const unsigned short*)(ws + WS_CAND);
  const int* cntg = (const int*)ws + WS_CCNT;

  // ---- z-slab load (r12/r15-verified): 4096 float4 chunks, coalesced
  //      along tokens; chunk c -> d = c>>4, tok4 = (c&15)*4 ----
#pragma unroll
  for (int it = 0; it < 8; it++) {
    int c = it * 512 + tid;
    int d = c >> 4, t4 = (c & 15) << 2;
    float4 v4 = *(const float4*)(zb + (size_t)d * SPATIAL + t4);
    zs[(t4 + 0) * ZLD + d] = v4.x;
    zs[(t4 + 1) * ZLD + d] = v4.y;
    zs[(t4 + 2) * ZLD + d] = v4.z;
    zs[(t4 + 3) * ZLD + d] = v4.w;
  }
  if (tid < TOK_BLK) {  // per-token state init
    int cc = cntg[n0 + tid];
    cntl[tid] = cc;
    pre[tid] = (cc > CAP) ? K_CODES : cc;  // overflow => all 1024 codes
    Szs[tid] = ws[WS_SZ + n0 + tid];
    best[tid] = 0xFFFFFFFFFFFFFFFFULL;
  }
  __syncthreads();
  if (tid == 0) {  // 64-entry serial prefix (cheap in LDS)
    int s = 0;
    for (int t = 0; t < TOK_BLK; t++) { int v = pre[t]; pre[t] = s; s += v; }
    pre[TOK_BLK] = s;
  }
  __syncthreads();
  int T = pre[TOK_BLK];

  // ---- D-part: task i -> (token t, slot j) via binary search; each task
  //      runs the UNCHANGED exact ascending-d fmaf chain and lex-min-merges
  //      via packed atomicMin (bit-exact (D,k) ordering). ----
  for (int i = tid; i < T; i += 512) {
    int lo = 0, hi = TOK_BLK - 1;
    while (lo < hi) {  // largest t with pre[t] <= i
      int mid = (lo + hi + 1) >> 1;
      if (pre[mid] <= i) lo = mid; else hi = mid - 1;
    }
    int t = lo, j = i - pre[t];
    int k = (cntl[t] > CAP) ? j : (int)candg[(size_t)(n0 + t) * CAP + j];
    const float* er = e + (size_t)k * DIM;
    const float* zp = zs + t * ZLD;
    float acc = 0.f;
#pragma unroll 4
    for (int dd = 0; dd < DIM; dd += 4) {
      float4 e4 = *(const float4*)(er + dd);
      acc = fmaf(zp[dd + 0], e4.x, acc);
      acc = fmaf(zp[dd + 1], e4.y, acc);
      acc = fmaf(zp[dd + 2], e4.z, acc);
      acc = fmaf(zp[dd + 3], e4.w, acc);
    }
    float D = __fsub_rn(__fadd_rn(Szs[t], Se[k]), __fmul_rn(2.f, acc));
    atomicMin(&best[t], packDK(D, k));
  }
  __syncthreads();
  if (tid < TOK_BLK) {
    int k = (int)(best[tid] & 0xFFFFFFFFu);
    mini_sh[tid] = k;
    out[O_IDX + n0 + tid] = (float)k;
  }
  __syncthreads();  // mini_sh ready

  // ---- E-part (r13/r15-verified form): lane = token; wave w covers dims
  //      [w*32, w*32+32); z from slab ((lane+d)%32 -> 2-way-free) ----
  int mten = mini_sh[lane];
  const float* erow = e + (size_t)mten * DIM;
  const float* zrow = zs + lane * ZLD;
  float* op = out + (size_t)b * DIM * SPATIAL + s0;
  float sumsq = 0.f;
#pragma unroll 2
  for (int i4 = 0; i4 < 32; i4 += 4) {
    int d = w * 32 + i4;  // wave-uniform d, 16B-aligned
    float4 v4 = *(const float4*)(erow + d);
#pragma unroll
    for (int m = 0; m < 4; m++) {
      float v = (m == 0) ? v4.x : (m == 1) ? v4.y : (m == 2) ? v4.z : v4.w;
      float zv = zrow[d + m];
      float df = __fsub_rn(v, zv);
      sumsq = fmaf(df, df, sumsq);
      op[(size_t)(d + m) * SPATIAL + lane] = v;  // coalesced 64-wide store
    }
  }
#pragma unroll
  for (int o = 32; o > 0; o >>= 1) sumsq += __shfl_down(sumsq, o, 64);
  if (lane == 0) red[w] = sumsq;
  __syncthreads();
  if (tid == 0) {
    float rs = ((red[0] + red[1]) + (red[2] + red[3])) +
               ((red[4] + red[5]) + (red[6] + red[7]));
    atomicAdd(ws + WS_LOSS, rs);
    __threadfence();  // loss add globally visible before counter bump
    unsigned t = atomicAdd((unsigned*)ws + WS_CNT, 1u);
    if (t == NBLK - 1) {  // last DE block publishes loss
      float total = atomicAdd(ws + WS_LOSS, 0.f);  // device-scope read
      out[O_LOSS] = 1.25f * total / 8388608.f;
    }
  }
}

extern "C" void kernel_launch(void* const* d_in, const int* in_sizes, int n_in,
                              void* d_out, int out_size, void* d_ws, size_t ws_size,
                              hipStream_t stream) {
  const float* z = (const float*)d_in[0];
  const float* e = (const float*)d_in[1];
  float* ws = (float*)d_ws;
  float* out = (float*)d_out;

  prep_kernel<<<K_CODES, 256, 0, stream>>>(e, ws);
  filter_kernel<<<NBLK, 512, 0, stream>>>(z, ws);
  de_kernel<<<NBLK, 512, 0, stream>>>(z, e, ws, out);
}